// Round 6
// baseline (536.449 us; speedup 1.0000x reference)
//
#include <hip/hip_runtime.h>

typedef unsigned short u16;
typedef u16   u16x4 __attribute__((ext_vector_type(4)));
typedef u16   u16x8 __attribute__((ext_vector_type(8)));
typedef short s16x8 __attribute__((ext_vector_type(8)));
typedef float f32x4 __attribute__((ext_vector_type(4)));

__device__ __forceinline__ float b2f(u16 u) {
    union { unsigned int i; float f; } v; v.i = ((unsigned int)u) << 16; return v.f;
}
__device__ __forceinline__ u16 f2b(float f) {
    union { float f; unsigned int i; } v; v.f = f;
    unsigned int r = v.i + 0x7fffu + ((v.i >> 16) & 1u);
    return (u16)(r >> 16);
}
__device__ __forceinline__ float gelu_f(float x) {
    float z = 0.7978845608028654f * (x + 0.044715f * x * x * x);
    float e = __expf(2.0f * z);
    float t = 1.0f - 2.0f / (e + 1.0f);   // tanh(z), safe at e=inf
    return 0.5f * x * (1.0f + t);
}
__device__ __forceinline__ void async16(const u16* g, u16* l) {
    __builtin_amdgcn_global_load_lds(
        (const __attribute__((address_space(1))) unsigned int*)g,
        (__attribute__((address_space(3))) unsigned int*)l,
        16, 0, 0);
}

// ---- dtype detector: bf16-read exponent >= 2^60 anywhere => fp32 input
__global__ __launch_bounds__(256)
void detect_k(const u16* __restrict__ x, int* __restrict__ flag)
{
    int tid = threadIdx.x;
    int bad = 0;
    for (int i = tid; i < 65536; i += 256) {
        int e = (x[i] >> 7) & 0xFF;
        if (e >= 187) bad = 1;
    }
    unsigned long long m = __ballot(bad != 0);
    __shared__ int sh[4];
    if ((tid & 63) == 0) sh[tid >> 6] = (m != 0ull) ? 1 : 0;
    __syncthreads();
    if (tid == 0) flag[0] = sh[0] | sh[1] | sh[2] | sh[3];
}

// ---- fused big-tensor converter (vec4): x|w_in|w_out|w_fc|w_proj -> ws[0..16Mi)
__global__ __launch_bounds__(256)
void conv_big_k(const void* __restrict__ s0, const void* __restrict__ s1,
                const void* __restrict__ s2, const void* __restrict__ s3,
                const void* __restrict__ s4, u16* __restrict__ dst,
                const int* __restrict__ flag)
{
    const long MEG = 1L << 20;
    long gid = ((long)blockIdx.x * 256 + threadIdx.x) * 4;   // < 16Mi
    const void* s; long off;
    if      (gid <  4*MEG) { s = s0; off = gid; }
    else if (gid <  7*MEG) { s = s1; off = gid - 4*MEG; }
    else if (gid <  8*MEG) { s = s2; off = gid - 7*MEG; }
    else if (gid < 12*MEG) { s = s3; off = gid - 8*MEG; }
    else                   { s = s4; off = gid - 12*MEG; }
    u16x4 o;
    if (*flag) {
        const float4 f = *(const float4*)((const float*)s + off);
        o[0] = f2b(f.x); o[1] = f2b(f.y); o[2] = f2b(f.z); o[3] = f2b(f.w);
    } else {
        o = *(const u16x4*)((const u16*)s + off);
    }
    *(u16x4*)(dst + gid) = o;
}

// ---- fused small-param converter into 4Ki-slotted region
__global__ __launch_bounds__(256)
void conv_small_k(const void* s0, const void* s1, const void* s2, const void* s3,
                  const void* s4, const void* s5, const void* s6, const void* s7,
                  u16* __restrict__ dst, const int* __restrict__ flag)
{
    int gid = blockIdx.x * 256 + threadIdx.x;          // < 13312
    int seg, off;
    if      (gid <  4096) { seg = gid >> 10;  off = gid & 1023; }
    else if (gid <  7168) { seg = 4; off = gid - 4096; }
    else if (gid <  8192) { seg = 5; off = gid - 7168; }
    else if (gid < 12288) { seg = 6; off = gid - 8192; }
    else                  { seg = 7; off = gid - 12288; }
    const void* srcs[8] = {s0, s1, s2, s3, s4, s5, s6, s7};
    const void* s = srcs[seg];
    dst[seg * 4096 + off] = (*flag) ? f2b(((const float*)s)[off]) : ((const u16*)s)[off];
}

// ---------------- LayerNorm: one block per row of 1024 ----------------
__global__ __launch_bounds__(256)
void ln_k(const u16* __restrict__ x, const u16* __restrict__ g,
          const u16* __restrict__ b, u16* __restrict__ o)
{
    long row = blockIdx.x;
    int tid = threadIdx.x;
    const u16x4 u = *(const u16x4*)(x + row * 1024 + tid * 4);
    float v0 = b2f(u[0]), v1 = b2f(u[1]), v2 = b2f(u[2]), v3 = b2f(u[3]);
    float s  = v0 + v1 + v2 + v3;
    float sq = v0*v0 + v1*v1 + v2*v2 + v3*v3;
    #pragma unroll
    for (int off = 32; off; off >>= 1) { s += __shfl_xor(s, off); sq += __shfl_xor(sq, off); }
    __shared__ float sm[8];
    int wid = tid >> 6, lane = tid & 63;
    if (lane == 0) { sm[wid] = s; sm[wid + 4] = sq; }
    __syncthreads();
    s  = sm[0] + sm[1] + sm[2] + sm[3];
    sq = sm[4] + sm[5] + sm[6] + sm[7];
    float mean = s * (1.0f / 1024.0f);
    float var  = sq * (1.0f / 1024.0f) - mean * mean;
    float rs   = rsqrtf(var + 1e-5f);
    u16x4 gg = *(const u16x4*)(g + tid * 4);
    u16x4 bb = *(const u16x4*)(b + tid * 4);
    u16x4 ov;
    ov[0] = f2b((v0 - mean) * rs * b2f(gg[0]) + b2f(bb[0]));
    ov[1] = f2b((v1 - mean) * rs * b2f(gg[1]) + b2f(bb[1]));
    ov[2] = f2b((v2 - mean) * rs * b2f(gg[2]) + b2f(bb[2]));
    ov[3] = f2b((v3 - mean) * rs * b2f(gg[3]) + b2f(bb[3]));
    *(u16x4*)(o + row * 1024 + tid * 4) = ov;
}

// -------- Softmax (causal, in-place), one wave per row --------
__global__ __launch_bounds__(256)
void softmax_k(u16* __restrict__ probs)
{
    int wid = threadIdx.x >> 6, lane = threadIdx.x & 63;
    long rid = (long)blockIdx.x * 4 + wid;          // chunk*16384 rows
    int q = (int)(rid & 1023);
    int tile_end = ((q >> 7) + 1) << 7;
    u16* row = probs + rid * 1024;
    float v[16];
    float m = -3.0e38f;
    #pragma unroll
    for (int c = 0; c < 2; c++) {
        int kb = (c * 64 + lane) * 8;
        if (kb <= q) {
            u16x8 u = *(const u16x8*)(row + kb);
            #pragma unroll
            for (int e = 0; e < 8; e++) {
                if (kb + e <= q) {
                    float f = b2f(u[e]);
                    v[c * 8 + e] = f;
                    m = fmaxf(m, f);
                } else v[c * 8 + e] = -3.0e38f;
            }
        } else {
            #pragma unroll
            for (int e = 0; e < 8; e++) v[c * 8 + e] = -3.0e38f;
        }
    }
    #pragma unroll
    for (int off = 32; off; off >>= 1) m = fmaxf(m, __shfl_xor(m, off));
    float s = 0.0f;
    #pragma unroll
    for (int t = 0; t < 16; t++) {
        float e = (v[t] > -1.0e38f) ? __expf(v[t] - m) : 0.0f;
        v[t] = e; s += e;
    }
    #pragma unroll
    for (int off = 32; off; off >>= 1) s += __shfl_xor(s, off);
    float inv = 1.0f / s;
    #pragma unroll
    for (int c = 0; c < 2; c++) {
        int kb = (c * 64 + lane) * 8;
        if (kb < tile_end) {
            u16x8 o;
            #pragma unroll
            for (int e = 0; e < 8; e++) o[e] = f2b(v[c * 8 + e] * inv);
            *(u16x8*)(row + kb) = o;
        }
    }
}

// -------- mean over heads -> att_weights; chunk-aware, skips upper tri
__global__ __launch_bounds__(256)
void mean_k(const u16* __restrict__ probs, void* __restrict__ ow, long ofs,
            const int* __restrict__ flag)
{
    const long MEG = 1L << 20;
    long vid = (long)blockIdx.x * 256 + threadIdx.x;
    int  bl  = (int)(vid >> 17);
    long r   = vid & 131071;
    long base = r * 8;
    int qq = (int)(base >> 10), k0 = (int)(base & 1023);
    float s[8] = {0,0,0,0,0,0,0,0};
    if (k0 <= qq) {
        const u16* pb = probs + ((long)bl << 24);
        for (int h = 0; h < 16; h++) {
            const u16x8 u = *(const u16x8*)(pb + (((long)h << 20) + (long)qq * 1024 + k0));
            #pragma unroll
            for (int e = 0; e < 8; e++) s[e] += b2f(u[e]);
        }
    }
    long idx = ofs + (long)bl * MEG + base;
    if (*flag) {
        float* o = (float*)ow + idx;
        #pragma unroll
        for (int e = 0; e < 8; e++) o[e] = s[e] * 0.0625f;
    } else {
        u16x8 o;
        #pragma unroll
        for (int e = 0; e < 8; e++) o[e] = f2b(s[e] * 0.0625f);
        *(u16x8*)((u16*)ow + idx) = o;
    }
}

// -------- split-K reduce: out = sum_s P[s] + bias + res --------------
// MODE 0: bf16 store; MODE 1: flag-adaptive store (final output)
template<int NS, int MODE>
__global__ __launch_bounds__(256)
void reduce_k(const float* __restrict__ P, long slice,
              const u16* __restrict__ bias, const u16* __restrict__ res,
              void* __restrict__ out, const int* __restrict__ flag)
{
    long i = ((long)blockIdx.x * 256 + threadIdx.x) * 4;
    int gn = (int)(i & 1023);
    float4 v = *(const float4*)(P + i);
    #pragma unroll
    for (int s = 1; s < NS; s++) {
        const float4 p = *(const float4*)(P + (long)s * slice + i);
        v.x += p.x; v.y += p.y; v.z += p.z; v.w += p.w;
    }
    u16x4 bb = *(const u16x4*)(bias + gn);
    u16x4 rr = *(const u16x4*)(res + i);
    v.x += b2f(bb[0]) + b2f(rr[0]);
    v.y += b2f(bb[1]) + b2f(rr[1]);
    v.z += b2f(bb[2]) + b2f(rr[2]);
    v.w += b2f(bb[3]) + b2f(rr[3]);
    if (MODE == 1 && *flag) {
        *(float4*)((float*)out + i) = v;
    } else {
        u16x4 o;
        o[0] = f2b(v.x); o[1] = f2b(v.y); o[2] = f2b(v.z); o[3] = f2b(v.w);
        *(u16x4*)((u16*)out + i) = o;
    }
}

// ---------------- gemm_bt: C[m,n] = sum_k A[m,k]*Bt[n,k] + epilogue ---
// Single-barrier double-buffered K-loop.
// EPI: 1 qkv-routing (+bias), 2 +bias+residual (bf16), 3 gelu(+bias),
//      4 scores (scale+causal, tn<=tm only), 5 PV (k-limit, bz=b*16+h),
//      6 +bias+residual flag-adaptive, 7 split-K fp32 partial (bz=k-slice)
template<int BN, int EPI>
__global__ __launch_bounds__(256)
void gemm_bt(const u16* __restrict__ A, const u16* __restrict__ Bt,
             u16* __restrict__ C, const u16* __restrict__ bias,
             const u16* __restrict__ res,
             u16* __restrict__ qb, u16* __restrict__ kb, u16* __restrict__ vb,
             int M, int N, int K, int lda, int ldb, int ldc,
             long sA, long sB, long sC,
             const int* __restrict__ oflag, void* __restrict__ oout)
{
    constexpr int BM = 128, BK = 32;
    constexpr int WROWS = (BN == 128) ? 2 : 4;
    constexpr int WCOLS = (BN == 128) ? 2 : 1;
    constexpr int WM = BM / WROWS, WN = BN / WCOLS;
    constexpr int MI = WM / 16, NJ = WN / 16;
    constexpr int BCH = BN * BK / 8 / 256;

    __shared__ alignas(16) u16 Ash[2][BM * BK];
    __shared__ alignas(16) u16 Bsh[2][BN * BK];

    const int tid = threadIdx.x;
    int tn = blockIdx.x, tm = blockIdx.y;
    const int bz = blockIdx.z;
    if (EPI == 4 && tn > tm) return;   // fully-masked causal tile

    // XCD-aware swizzle: all 16(+) blocks sharing an A-panel land on one XCD
    if (EPI == 1 || EPI == 2 || EPI == 3 || EPI == 6 || EPI == 7) {
        int L = blockIdx.y * gridDim.x + blockIdx.x;
        int xcd = L & 7, idx = L >> 3;
        tn = idx % gridDim.x;
        tm = (idx / gridDim.x) * 8 + xcd;   // gridDim.y % 8 == 0 required
    }

    const u16* Ab = A + (long)bz * sA;
    const u16* Bb = Bt + (long)bz * sB;

    const int m0 = tm * BM, n0 = tn * BN;
    const int kEff = (EPI == 5) ? (((tm + 1) * BM < K) ? (tm + 1) * BM : K) : K;

    const int w = tid >> 6, lane = tid & 63;
    const int wrow = w % WROWS, wcol = w / WROWS;
    const int mw = wrow * WM, nw = wcol * WN;
    const int lr = lane & 15, quad = lane >> 4;

    const int ca0 = tid, ca1 = 256 + tid;
    const int ar0 = ca0 >> 2, ac0 = (ca0 & 3) * 8;
    const int ar1 = ca1 >> 2, ac1 = (ca1 & 3) * 8;
    const int br0 = tid >> 2, bc0 = (tid & 3) * 8;
    const int cb1 = 256 + tid;
    const int br1 = cb1 >> 2, bc1 = (cb1 & 3) * 8;

    auto stage = [&](int buf, int k0) {
        async16(Ab + (long)(m0 + ar0) * lda + k0 + ac0, &Ash[buf][ca0 * 8]);
        async16(Ab + (long)(m0 + ar1) * lda + k0 + ac1, &Ash[buf][ca1 * 8]);
        async16(Bb + (long)(n0 + br0) * ldb + k0 + bc0, &Bsh[buf][tid * 8]);
        if (BCH == 2)
            async16(Bb + (long)(n0 + br1) * ldb + k0 + bc1, &Bsh[buf][cb1 * 8]);
    };

    f32x4 acc[MI][NJ] = {};

    stage(0, 0);
    int cur = 0;
    for (int k0 = 0; k0 < kEff; k0 += BK) {
        __syncthreads();
        if (k0 + BK < kEff) stage(cur ^ 1, k0 + BK);

        s16x8 af[MI], bfr[NJ];
        #pragma unroll
        for (int i = 0; i < MI; i++)
            af[i] = *(const s16x8*)&Ash[cur][(mw + i * 16 + lr) * BK + quad * 8];
        #pragma unroll
        for (int j = 0; j < NJ; j++)
            bfr[j] = *(const s16x8*)&Bsh[cur][(nw + j * 16 + lr) * BK + quad * 8];
        #pragma unroll
        for (int i = 0; i < MI; i++)
            #pragma unroll
            for (int j = 0; j < NJ; j++)
                acc[i][j] = __builtin_amdgcn_mfma_f32_16x16x32_bf16(af[i], bfr[j], acc[i][j], 0, 0, 0);
        cur ^= 1;
    }

    u16* Cb;
    if (EPI == 5) Cb = C + (long)(bz >> 4) * (1 << 20) + (bz & 15) * 64;
    else          Cb = C + (long)bz * sC;

    #pragma unroll
    for (int i = 0; i < MI; i++) {
        #pragma unroll
        for (int j = 0; j < NJ; j++) {
            #pragma unroll
            for (int r = 0; r < 4; r++) {
                int gm = m0 + mw + i * 16 + quad * 4 + r;
                int gn = n0 + nw + j * 16 + lr;
                float v = acc[i][j][r];
                if (EPI == 5) {
                    Cb[(long)gm * ldc + gn] = f2b(v);
                } else if (EPI == 1) {
                    v += b2f(bias[gn]);
                    int b = gm >> 10, s = gm & 1023;
                    int sel = gn >> 10, nn = gn & 1023, hh = nn >> 6, d = nn & 63;
                    long bh = b * 16 + hh;
                    if (sel == 0)      qb[(bh * 1024 + s) * 64 + d] = f2b(v);
                    else if (sel == 1) kb[(bh * 1024 + s) * 64 + d] = f2b(v);
                    else               vb[(bh * 64 + d) * 1024 + s] = f2b(v);
                } else if (EPI == 2) {
                    v += b2f(bias[gn]) + b2f(res[(long)gm * ldc + gn]);
                    Cb[(long)gm * ldc + gn] = f2b(v);
                } else if (EPI == 3) {
                    Cb[(long)gm * ldc + gn] = f2b(gelu_f(v + b2f(bias[gn])));
                } else if (EPI == 4) {
                    if (gn <= gm) Cb[(long)gm * ldc + gn] = f2b(v * 0.125f);
                } else if (EPI == 6) {
                    v += b2f(bias[gn]) + b2f(res[(long)gm * ldc + gn]);
                    long idx = (long)gm * ldc + gn;
                    if (*oflag) ((float*)oout)[idx] = v;
                    else        ((u16*)oout)[idx]   = f2b(v);
                } else if (EPI == 7) {
                    ((float*)oout)[(long)bz * sC + (long)gm * ldc + gn] = v;
                }
            }
        }
    }
}

extern "C" void kernel_launch(void* const* d_in, const int* in_sizes, int n_in,
                              void* d_out, int out_size, void* d_ws, size_t ws_size,
                              hipStream_t stream)
{
    const long MEG = 1L << 20;
    const long KI  = 1024;

    u16* ws = (u16*)d_ws;
    u16* xc    = ws;                    // 4Mi (becomes x2 in-place)
    u16* winC  = ws + 4  * MEG;
    u16* woutC = ws + 7  * MEG;
    u16* wfcC  = ws + 8  * MEG;
    u16* wprjC = ws + 12 * MEG;
    u16* sm    = ws + 16 * MEG;
    u16* ln1g = sm + 0*4*KI, *ln1b = sm + 1*4*KI;
    u16* ln2g = sm + 2*4*KI, *ln2b = sm + 3*4*KI;
    u16* binC = sm + 4*4*KI;
    u16* boutC= sm + 5*4*KI;
    u16* bfcC = sm + 6*4*KI;
    u16* bprjC= sm + 7*4*KI;
    int* flag = (int*)(sm + 8*4*KI);
    u16* slotA = ws + 16 * MEG + 64 * KI;
    u16* qB    = slotA + 4  * MEG;
    u16* kB    = slotA + 8  * MEG;
    u16* vT    = slotA + 12 * MEG;
    u16* probs = slotA + 16 * MEG;      // chunk*(H,S,S); [0,16Mi) reused as act
    float* part = (float*)(probs + 16 * MEG);  // split-K partials (needs chunk=4)

    const long fixed_elems = 32 * MEG + 64 * KI;
    const long avail = (long)(ws_size / 2);
    int chunk = 1;
    if      (avail >= fixed_elems + 64 * MEG) chunk = 4;
    else if (avail >= fixed_elems + 32 * MEG) chunk = 2;
    const bool splitk = (chunk == 4);   // partials live beyond act in probs region

    detect_k<<<1, 256, 0, stream>>>((const u16*)d_in[0], flag);
    conv_big_k<<<16384, 256, 0, stream>>>(d_in[0], d_in[6], d_in[8], d_in[10],
                                          d_in[12], ws, flag);
    conv_small_k<<<52, 256, 0, stream>>>(d_in[2], d_in[3], d_in[4], d_in[5],
                                         d_in[7], d_in[9], d_in[11], d_in[13],
                                         sm, flag);

    u16* h   = slotA;
    u16* att = slotA;
    u16* h2  = slotA;
    u16* act = probs;

    // 1. LN1
    ln_k<<<4096, 256, 0, stream>>>(xc, ln1g, ln1b, h);
    // 2. QKV projection
    gemm_bt<128, 1><<<dim3(24, 32, 1), 256, 0, stream>>>(
        h, winC, nullptr, binC, nullptr, qB, kB, vT,
        4096, 3072, 1024, 1024, 1024, 0, 0, 0, 0, nullptr, nullptr);
    // 3-6. attention
    for (int b0 = 0; b0 < 4; b0 += chunk) {
        gemm_bt<128, 4><<<dim3(8, 8, 16 * chunk), 256, 0, stream>>>(
            qB + b0 * MEG, kB + b0 * MEG, probs, nullptr, nullptr,
            nullptr, nullptr, nullptr,
            1024, 1024, 64, 64, 64, 1024, 65536, 65536, 1048576, nullptr, nullptr);
        softmax_k<<<4096 * chunk, 256, 0, stream>>>(probs);
        gemm_bt<64, 5><<<dim3(1, 8, 16 * chunk), 256, 0, stream>>>(
            probs, vT + b0 * MEG, att + b0 * MEG, nullptr, nullptr,
            nullptr, nullptr, nullptr,
            1024, 64, 1024, 1024, 1024, 1024, 1048576, 65536, 0, nullptr, nullptr);
        mean_k<<<512 * chunk, 256, 0, stream>>>(probs, d_out, 4 * MEG + b0 * MEG, flag);
    }
    // 7. x2 = x + att @ w_out^T + b_out   (in-place over xc)
    if (splitk) {
        gemm_bt<64, 7><<<dim3(16, 32, 2), 256, 0, stream>>>(
            att, woutC, nullptr, nullptr, nullptr, nullptr, nullptr, nullptr,
            4096, 1024, 512, 1024, 1024, 1024, 512, 512, 4 * MEG, nullptr, part);
        reduce_k<2, 0><<<4096, 256, 0, stream>>>(part, 4 * MEG, boutC, xc, xc, flag);
    } else {
        gemm_bt<64, 2><<<dim3(16, 32, 1), 256, 0, stream>>>(
            att, woutC, xc, boutC, xc, nullptr, nullptr, nullptr,
            4096, 1024, 1024, 1024, 1024, 1024, 0, 0, 0, nullptr, nullptr);
    }
    // 8. LN2
    ln_k<<<4096, 256, 0, stream>>>(xc, ln2g, ln2b, h2);
    // 9. act = gelu(h2 @ w_fc^T + b_fc)
    gemm_bt<128, 3><<<dim3(32, 32, 1), 256, 0, stream>>>(
        h2, wfcC, act, bfcC, nullptr, nullptr, nullptr, nullptr,
        4096, 4096, 1024, 1024, 1024, 4096, 0, 0, 0, nullptr, nullptr);
    // 10. out = x2 + act @ w_proj^T + b_proj
    if (splitk) {
        gemm_bt<64, 7><<<dim3(16, 32, 4), 256, 0, stream>>>(
            act, wprjC, nullptr, nullptr, nullptr, nullptr, nullptr, nullptr,
            4096, 1024, 1024, 4096, 4096, 1024, 1024, 1024, 4 * MEG, nullptr, part);
        reduce_k<4, 1><<<4096, 256, 0, stream>>>(part, 4 * MEG, bprjC, xc, d_out, flag);
    } else {
        gemm_bt<64, 6><<<dim3(16, 32, 1), 256, 0, stream>>>(
            act, wprjC, nullptr, bprjC, xc, nullptr, nullptr, nullptr,
            4096, 1024, 4096, 4096, 4096, 1024, 0, 0, 0, flag, d_out);
    }
}

// Round 7
// 519.008 us; speedup vs baseline: 1.0336x; 1.0336x over previous
//
#include <hip/hip_runtime.h>

typedef unsigned short u16;
typedef u16   u16x4 __attribute__((ext_vector_type(4)));
typedef u16   u16x8 __attribute__((ext_vector_type(8)));
typedef short s16x8 __attribute__((ext_vector_type(8)));
typedef float f32x4 __attribute__((ext_vector_type(4)));

__device__ __forceinline__ float b2f(u16 u) {
    union { unsigned int i; float f; } v; v.i = ((unsigned int)u) << 16; return v.f;
}
__device__ __forceinline__ u16 f2b(float f) {
    union { float f; unsigned int i; } v; v.f = f;
    unsigned int r = v.i + 0x7fffu + ((v.i >> 16) & 1u);
    return (u16)(r >> 16);
}
__device__ __forceinline__ float gelu_f(float x) {
    float z = 0.7978845608028654f * (x + 0.044715f * x * x * x);
    float e = __expf(2.0f * z);
    float t = 1.0f - 2.0f / (e + 1.0f);
    return 0.5f * x * (1.0f + t);
}
__device__ __forceinline__ void async16(const u16* g, u16* l) {
    __builtin_amdgcn_global_load_lds(
        (const __attribute__((address_space(1))) unsigned int*)g,
        (__attribute__((address_space(3))) unsigned int*)l,
        16, 0, 0);
}

// ---- dtype detector: bf16-read exponent >= 2^60 anywhere => fp32 input
__global__ __launch_bounds__(256)
void detect_k(const u16* __restrict__ x, int* __restrict__ flag)
{
    int tid = threadIdx.x;
    int bad = 0;
    for (int i = tid; i < 65536; i += 256) {
        int e = (x[i] >> 7) & 0xFF;
        if (e >= 187) bad = 1;
    }
    unsigned long long m = __ballot(bad != 0);
    __shared__ int sh[4];
    if ((tid & 63) == 0) sh[tid >> 6] = (m != 0ull) ? 1 : 0;
    __syncthreads();
    if (tid == 0) flag[0] = sh[0] | sh[1] | sh[2] | sh[3];
}

// ---- weight converter (vec4): w_in|w_out|w_fc|w_proj -> ws[4Mi..16Mi)
__global__ __launch_bounds__(256)
void conv_w_k(const void* __restrict__ s0, const void* __restrict__ s1,
              const void* __restrict__ s2, const void* __restrict__ s3,
              u16* __restrict__ dst, const int* __restrict__ flag)
{
    const long MEG = 1L << 20;
    long gid = ((long)blockIdx.x * 256 + threadIdx.x) * 4;   // < 12Mi
    const void* s; long off;
    if      (gid <  3*MEG) { s = s0; off = gid; }
    else if (gid <  4*MEG) { s = s1; off = gid - 3*MEG; }
    else if (gid <  8*MEG) { s = s2; off = gid - 4*MEG; }
    else                   { s = s3; off = gid - 8*MEG; }
    u16x4 o;
    if (*flag) {
        const float4 f = *(const float4*)((const float*)s + off);
        o[0] = f2b(f.x); o[1] = f2b(f.y); o[2] = f2b(f.z); o[3] = f2b(f.w);
    } else {
        o = *(const u16x4*)((const u16*)s + off);
    }
    *(u16x4*)(dst + gid) = o;
}

// ---- fused small-param converter into 4Ki-slotted region
__global__ __launch_bounds__(256)
void conv_small_k(const void* s0, const void* s1, const void* s2, const void* s3,
                  const void* s4, const void* s5, const void* s6, const void* s7,
                  u16* __restrict__ dst, const int* __restrict__ flag)
{
    int gid = blockIdx.x * 256 + threadIdx.x;          // < 13312
    int seg, off;
    if      (gid <  4096) { seg = gid >> 10;  off = gid & 1023; }
    else if (gid <  7168) { seg = 4; off = gid - 4096; }
    else if (gid <  8192) { seg = 5; off = gid - 7168; }
    else if (gid < 12288) { seg = 6; off = gid - 8192; }
    else                  { seg = 7; off = gid - 12288; }
    const void* srcs[8] = {s0, s1, s2, s3, s4, s5, s6, s7};
    const void* s = srcs[seg];
    dst[seg * 4096 + off] = (*flag) ? f2b(((const float*)s)[off]) : ((const u16*)s)[off];
}

// ---- LN1 fused with x conversion: reads raw x (flag-adaptive),
//      writes xc (bf16 copy of x) and h (LN output)
__global__ __launch_bounds__(256)
void ln1x_k(const void* __restrict__ xraw, const u16* __restrict__ g,
            const u16* __restrict__ b, u16* __restrict__ xc,
            u16* __restrict__ o, const int* __restrict__ flag)
{
    long row = blockIdx.x;
    int tid = threadIdx.x;
    float v0, v1, v2, v3;
    if (*flag) {
        const float4 f = *(const float4*)((const float*)xraw + row * 1024 + tid * 4);
        v0 = b2f(f2b(f.x)); v1 = b2f(f2b(f.y));   // round to bf16 first so
        v2 = b2f(f2b(f.z)); v3 = b2f(f2b(f.w));   // xc and LN agree exactly
    } else {
        const u16x4 u = *(const u16x4*)((const u16*)xraw + row * 1024 + tid * 4);
        v0 = b2f(u[0]); v1 = b2f(u[1]); v2 = b2f(u[2]); v3 = b2f(u[3]);
    }
    u16x4 xv; xv[0] = f2b(v0); xv[1] = f2b(v1); xv[2] = f2b(v2); xv[3] = f2b(v3);
    *(u16x4*)(xc + row * 1024 + tid * 4) = xv;
    float s  = v0 + v1 + v2 + v3;
    float sq = v0*v0 + v1*v1 + v2*v2 + v3*v3;
    #pragma unroll
    for (int off = 32; off; off >>= 1) { s += __shfl_xor(s, off); sq += __shfl_xor(sq, off); }
    __shared__ float sm[8];
    int wid = tid >> 6, lane = tid & 63;
    if (lane == 0) { sm[wid] = s; sm[wid + 4] = sq; }
    __syncthreads();
    s  = sm[0] + sm[1] + sm[2] + sm[3];
    sq = sm[4] + sm[5] + sm[6] + sm[7];
    float mean = s * (1.0f / 1024.0f);
    float var  = sq * (1.0f / 1024.0f) - mean * mean;
    float rs   = rsqrtf(var + 1e-5f);
    u16x4 gg = *(const u16x4*)(g + tid * 4);
    u16x4 bb = *(const u16x4*)(b + tid * 4);
    u16x4 ov;
    ov[0] = f2b((v0 - mean) * rs * b2f(gg[0]) + b2f(bb[0]));
    ov[1] = f2b((v1 - mean) * rs * b2f(gg[1]) + b2f(bb[1]));
    ov[2] = f2b((v2 - mean) * rs * b2f(gg[2]) + b2f(bb[2]));
    ov[3] = f2b((v3 - mean) * rs * b2f(gg[3]) + b2f(bb[3]));
    *(u16x4*)(o + row * 1024 + tid * 4) = ov;
}

// ---- plain LN (fallback path)
__global__ __launch_bounds__(256)
void ln_k(const u16* __restrict__ x, const u16* __restrict__ g,
          const u16* __restrict__ b, u16* __restrict__ o)
{
    long row = blockIdx.x;
    int tid = threadIdx.x;
    const u16x4 u = *(const u16x4*)(x + row * 1024 + tid * 4);
    float v0 = b2f(u[0]), v1 = b2f(u[1]), v2 = b2f(u[2]), v3 = b2f(u[3]);
    float s  = v0 + v1 + v2 + v3;
    float sq = v0*v0 + v1*v1 + v2*v2 + v3*v3;
    #pragma unroll
    for (int off = 32; off; off >>= 1) { s += __shfl_xor(s, off); sq += __shfl_xor(sq, off); }
    __shared__ float sm[8];
    int wid = tid >> 6, lane = tid & 63;
    if (lane == 0) { sm[wid] = s; sm[wid + 4] = sq; }
    __syncthreads();
    s  = sm[0] + sm[1] + sm[2] + sm[3];
    sq = sm[4] + sm[5] + sm[6] + sm[7];
    float mean = s * (1.0f / 1024.0f);
    float var  = sq * (1.0f / 1024.0f) - mean * mean;
    float rs   = rsqrtf(var + 1e-5f);
    u16x4 gg = *(const u16x4*)(g + tid * 4);
    u16x4 bb = *(const u16x4*)(b + tid * 4);
    u16x4 ov;
    ov[0] = f2b((v0 - mean) * rs * b2f(gg[0]) + b2f(bb[0]));
    ov[1] = f2b((v1 - mean) * rs * b2f(gg[1]) + b2f(bb[1]));
    ov[2] = f2b((v2 - mean) * rs * b2f(gg[2]) + b2f(bb[2]));
    ov[3] = f2b((v3 - mean) * rs * b2f(gg[3]) + b2f(bb[3]));
    *(u16x4*)(o + row * 1024 + tid * 4) = ov;
}

// ---- fused split-K(2) reduce + LN2: x2 = P0+P1+bias+res (write back to res),
//      then h2 = LN(x2)
__global__ __launch_bounds__(256)
void redln_k(const float* __restrict__ P, long slice,
             const u16* __restrict__ bias, u16* __restrict__ res,
             const u16* __restrict__ g, const u16* __restrict__ b,
             u16* __restrict__ o)
{
    long row = blockIdx.x;
    int tid = threadIdx.x;
    long i = row * 1024 + tid * 4;
    float4 v  = *(const float4*)(P + i);
    float4 p1 = *(const float4*)(P + slice + i);
    u16x4 bb = *(const u16x4*)(bias + tid * 4);
    u16x4 rr = *(const u16x4*)(res + i);
    float v0 = b2f(f2b(v.x + p1.x + b2f(bb[0]) + b2f(rr[0])));
    float v1 = b2f(f2b(v.y + p1.y + b2f(bb[1]) + b2f(rr[1])));
    float v2 = b2f(f2b(v.z + p1.z + b2f(bb[2]) + b2f(rr[2])));
    float v3 = b2f(f2b(v.w + p1.w + b2f(bb[3]) + b2f(rr[3])));
    u16x4 xv; xv[0] = f2b(v0); xv[1] = f2b(v1); xv[2] = f2b(v2); xv[3] = f2b(v3);
    *(u16x4*)(res + i) = xv;
    float s  = v0 + v1 + v2 + v3;
    float sq = v0*v0 + v1*v1 + v2*v2 + v3*v3;
    #pragma unroll
    for (int off = 32; off; off >>= 1) { s += __shfl_xor(s, off); sq += __shfl_xor(sq, off); }
    __shared__ float sm[8];
    int wid = tid >> 6, lane = tid & 63;
    if (lane == 0) { sm[wid] = s; sm[wid + 4] = sq; }
    __syncthreads();
    s  = sm[0] + sm[1] + sm[2] + sm[3];
    sq = sm[4] + sm[5] + sm[6] + sm[7];
    float mean = s * (1.0f / 1024.0f);
    float var  = sq * (1.0f / 1024.0f) - mean * mean;
    float rs   = rsqrtf(var + 1e-5f);
    u16x4 gg = *(const u16x4*)(g + tid * 4);
    u16x4 b2 = *(const u16x4*)(b + tid * 4);
    u16x4 ov;
    ov[0] = f2b((v0 - mean) * rs * b2f(gg[0]) + b2f(b2[0]));
    ov[1] = f2b((v1 - mean) * rs * b2f(gg[1]) + b2f(b2[1]));
    ov[2] = f2b((v2 - mean) * rs * b2f(gg[2]) + b2f(b2[2]));
    ov[3] = f2b((v3 - mean) * rs * b2f(gg[3]) + b2f(b2[3]));
    *(u16x4*)(o + row * 1024 + tid * 4) = ov;
}

// -------- Softmax (causal, in-place), one wave per row --------
__global__ __launch_bounds__(256)
void softmax_k(u16* __restrict__ probs)
{
    int wid = threadIdx.x >> 6, lane = threadIdx.x & 63;
    long rid = (long)blockIdx.x * 4 + wid;
    int q = (int)(rid & 1023);
    int tile_end = ((q >> 7) + 1) << 7;
    u16* row = probs + rid * 1024;
    float v[16];
    float m = -3.0e38f;
    #pragma unroll
    for (int c = 0; c < 2; c++) {
        int kb = (c * 64 + lane) * 8;
        if (kb <= q) {
            u16x8 u = *(const u16x8*)(row + kb);
            #pragma unroll
            for (int e = 0; e < 8; e++) {
                if (kb + e <= q) {
                    float f = b2f(u[e]);
                    v[c * 8 + e] = f;
                    m = fmaxf(m, f);
                } else v[c * 8 + e] = -3.0e38f;
            }
        } else {
            #pragma unroll
            for (int e = 0; e < 8; e++) v[c * 8 + e] = -3.0e38f;
        }
    }
    #pragma unroll
    for (int off = 32; off; off >>= 1) m = fmaxf(m, __shfl_xor(m, off));
    float s = 0.0f;
    #pragma unroll
    for (int t = 0; t < 16; t++) {
        float e = (v[t] > -1.0e38f) ? __expf(v[t] - m) : 0.0f;
        v[t] = e; s += e;
    }
    #pragma unroll
    for (int off = 32; off; off >>= 1) s += __shfl_xor(s, off);
    float inv = 1.0f / s;
    #pragma unroll
    for (int c = 0; c < 2; c++) {
        int kb = (c * 64 + lane) * 8;
        if (kb < tile_end) {
            u16x8 o;
            #pragma unroll
            for (int e = 0; e < 8; e++) o[e] = f2b(v[c * 8 + e] * inv);
            *(u16x8*)(row + kb) = o;
        }
    }
}

// -------- mean over heads -> att_weights --------
__global__ __launch_bounds__(256)
void mean_k(const u16* __restrict__ probs, void* __restrict__ ow, long ofs,
            const int* __restrict__ flag)
{
    const long MEG = 1L << 20;
    long vid = (long)blockIdx.x * 256 + threadIdx.x;
    int  bl  = (int)(vid >> 17);
    long r   = vid & 131071;
    long base = r * 8;
    int qq = (int)(base >> 10), k0 = (int)(base & 1023);
    float s[8] = {0,0,0,0,0,0,0,0};
    if (k0 <= qq) {
        const u16* pb = probs + ((long)bl << 24);
        for (int h = 0; h < 16; h++) {
            const u16x8 u = *(const u16x8*)(pb + (((long)h << 20) + (long)qq * 1024 + k0));
            #pragma unroll
            for (int e = 0; e < 8; e++) s[e] += b2f(u[e]);
        }
    }
    long idx = ofs + (long)bl * MEG + base;
    if (*flag) {
        float* o = (float*)ow + idx;
        #pragma unroll
        for (int e = 0; e < 8; e++) o[e] = s[e] * 0.0625f;
    } else {
        u16x8 o;
        #pragma unroll
        for (int e = 0; e < 8; e++) o[e] = f2b(s[e] * 0.0625f);
        *(u16x8*)((u16*)ow + idx) = o;
    }
}

// -------- split-K(4) reduce for final output --------
__global__ __launch_bounds__(256)
void reduce_out_k(const float* __restrict__ P, long slice,
                  const u16* __restrict__ bias, const u16* __restrict__ res,
                  void* __restrict__ out, const int* __restrict__ flag)
{
    long i = ((long)blockIdx.x * 256 + threadIdx.x) * 4;
    int gn = (int)(i & 1023);
    float4 v = *(const float4*)(P + i);
    #pragma unroll
    for (int s = 1; s < 4; s++) {
        const float4 p = *(const float4*)(P + (long)s * slice + i);
        v.x += p.x; v.y += p.y; v.z += p.z; v.w += p.w;
    }
    u16x4 bb = *(const u16x4*)(bias + gn);
    u16x4 rr = *(const u16x4*)(res + i);
    v.x += b2f(bb[0]) + b2f(rr[0]);
    v.y += b2f(bb[1]) + b2f(rr[1]);
    v.z += b2f(bb[2]) + b2f(rr[2]);
    v.w += b2f(bb[3]) + b2f(rr[3]);
    if (*flag) {
        *(float4*)((float*)out + i) = v;
    } else {
        u16x4 o;
        o[0] = f2b(v.x); o[1] = f2b(v.y); o[2] = f2b(v.z); o[3] = f2b(v.w);
        *(u16x4*)((u16*)out + i) = o;
    }
}

// ---------------- gemm_bt: C[m,n] = sum_k A[m,k]*Bt[n,k] + epilogue ---
// EPI: 1 qkv-routing (+bias), 2 +bias+residual (bf16), 3 gelu(+bias),
//      4 scores (scale+causal, tn<=tm only), 5 PV (k-limit, bz=b*16+h),
//      6 +bias+residual flag-adaptive, 7 split-K fp32 partial (bz=k-slice)
template<int BN, int EPI>
__global__ __launch_bounds__(256)
void gemm_bt(const u16* __restrict__ A, const u16* __restrict__ Bt,
             u16* __restrict__ C, const u16* __restrict__ bias,
             const u16* __restrict__ res,
             u16* __restrict__ qb, u16* __restrict__ kb, u16* __restrict__ vb,
             int M, int N, int K, int lda, int ldb, int ldc,
             long sA, long sB, long sC,
             const int* __restrict__ oflag, void* __restrict__ oout)
{
    constexpr int BM = 128, BK = 32;
    constexpr int WROWS = (BN == 128) ? 2 : 4;
    constexpr int WCOLS = (BN == 128) ? 2 : 1;
    constexpr int WM = BM / WROWS, WN = BN / WCOLS;
    constexpr int MI = WM / 16, NJ = WN / 16;
    constexpr int BCH = BN * BK / 8 / 256;

    __shared__ alignas(16) u16 Ash[2][BM * BK];
    __shared__ alignas(16) u16 Bsh[2][BN * BK];

    const int tid = threadIdx.x;
    int tn = blockIdx.x, tm = blockIdx.y;
    const int bz = blockIdx.z;
    if (EPI == 4 && tn > tm) return;

    // XCD-aware swizzle (A-panel locality); requires gridDim.y % 8 == 0
    if (EPI == 1 || EPI == 2 || EPI == 3 || EPI == 6 || EPI == 7) {
        int L = blockIdx.y * gridDim.x + blockIdx.x;
        int xcd = L & 7, idx = L >> 3;
        tn = idx % gridDim.x;
        tm = (idx / gridDim.x) * 8 + xcd;
    }

    const u16* Ab = A + (long)bz * sA;
    const u16* Bb = Bt + (long)bz * sB;

    const int m0 = tm * BM, n0 = tn * BN;
    const int kEff = (EPI == 5) ? (((tm + 1) * BM < K) ? (tm + 1) * BM : K) : K;

    const int w = tid >> 6, lane = tid & 63;
    const int wrow = w % WROWS, wcol = w / WROWS;
    const int mw = wrow * WM, nw = wcol * WN;
    const int lr = lane & 15, quad = lane >> 4;

    const int ca0 = tid, ca1 = 256 + tid;
    const int ar0 = ca0 >> 2, ac0 = (ca0 & 3) * 8;
    const int ar1 = ca1 >> 2, ac1 = (ca1 & 3) * 8;
    const int br0 = tid >> 2, bc0 = (tid & 3) * 8;
    const int cb1 = 256 + tid;
    const int br1 = cb1 >> 2, bc1 = (cb1 & 3) * 8;

    auto stage = [&](int buf, int k0) {
        async16(Ab + (long)(m0 + ar0) * lda + k0 + ac0, &Ash[buf][ca0 * 8]);
        async16(Ab + (long)(m0 + ar1) * lda + k0 + ac1, &Ash[buf][ca1 * 8]);
        async16(Bb + (long)(n0 + br0) * ldb + k0 + bc0, &Bsh[buf][tid * 8]);
        if (BCH == 2)
            async16(Bb + (long)(n0 + br1) * ldb + k0 + bc1, &Bsh[buf][cb1 * 8]);
    };

    f32x4 acc[MI][NJ] = {};

    stage(0, 0);
    int cur = 0;
    for (int k0 = 0; k0 < kEff; k0 += BK) {
        __syncthreads();
        if (k0 + BK < kEff) stage(cur ^ 1, k0 + BK);

        s16x8 af[MI], bfr[NJ];
        #pragma unroll
        for (int i = 0; i < MI; i++)
            af[i] = *(const s16x8*)&Ash[cur][(mw + i * 16 + lr) * BK + quad * 8];
        #pragma unroll
        for (int j = 0; j < NJ; j++)
            bfr[j] = *(const s16x8*)&Bsh[cur][(nw + j * 16 + lr) * BK + quad * 8];
        #pragma unroll
        for (int i = 0; i < MI; i++)
            #pragma unroll
            for (int j = 0; j < NJ; j++)
                acc[i][j] = __builtin_amdgcn_mfma_f32_16x16x32_bf16(af[i], bfr[j], acc[i][j], 0, 0, 0);
        cur ^= 1;
    }

    u16* Cb;
    if (EPI == 5) Cb = C + (long)(bz >> 4) * (1 << 20) + (bz & 15) * 64;
    else          Cb = C + (long)bz * sC;

    #pragma unroll
    for (int i = 0; i < MI; i++) {
        #pragma unroll
        for (int j = 0; j < NJ; j++) {
            #pragma unroll
            for (int r = 0; r < 4; r++) {
                int gm = m0 + mw + i * 16 + quad * 4 + r;
                int gn = n0 + nw + j * 16 + lr;
                float v = acc[i][j][r];
                if (EPI == 5) {
                    Cb[(long)gm * ldc + gn] = f2b(v);
                } else if (EPI == 1) {
                    v += b2f(bias[gn]);
                    int b = gm >> 10, s = gm & 1023;
                    int sel = gn >> 10, nn = gn & 1023, hh = nn >> 6, d = nn & 63;
                    long bh = b * 16 + hh;
                    if (sel == 0)      qb[(bh * 1024 + s) * 64 + d] = f2b(v);
                    else if (sel == 1) kb[(bh * 1024 + s) * 64 + d] = f2b(v);
                    else               vb[(bh * 64 + d) * 1024 + s] = f2b(v);
                } else if (EPI == 2) {
                    v += b2f(bias[gn]) + b2f(res[(long)gm * ldc + gn]);
                    Cb[(long)gm * ldc + gn] = f2b(v);
                } else if (EPI == 3) {
                    Cb[(long)gm * ldc + gn] = f2b(gelu_f(v + b2f(bias[gn])));
                } else if (EPI == 4) {
                    if (gn <= gm) Cb[(long)gm * ldc + gn] = f2b(v * 0.125f);
                } else if (EPI == 6) {
                    v += b2f(bias[gn]) + b2f(res[(long)gm * ldc + gn]);
                    long idx = (long)gm * ldc + gn;
                    if (*oflag) ((float*)oout)[idx] = v;
                    else        ((u16*)oout)[idx]   = f2b(v);
                } else if (EPI == 7) {
                    ((float*)oout)[(long)bz * sC + (long)gm * ldc + gn] = v;
                }
            }
        }
    }
}

extern "C" void kernel_launch(void* const* d_in, const int* in_sizes, int n_in,
                              void* d_out, int out_size, void* d_ws, size_t ws_size,
                              hipStream_t stream)
{
    const long MEG = 1L << 20;
    const long KI  = 1024;

    u16* ws = (u16*)d_ws;
    u16* xc    = ws;                    // 4Mi: bf16 x, becomes x2 in-place
    u16* winC  = ws + 4  * MEG;         // 3Mi
    u16* woutC = ws + 7  * MEG;         // 1Mi
    u16* wfcC  = ws + 8  * MEG;         // 4Mi
    u16* wprjC = ws + 12 * MEG;         // 4Mi
    u16* sm    = ws + 16 * MEG;
    u16* ln1g = sm + 0*4*KI, *ln1b = sm + 1*4*KI;
    u16* ln2g = sm + 2*4*KI, *ln2b = sm + 3*4*KI;
    u16* binC = sm + 4*4*KI;
    u16* boutC= sm + 5*4*KI;
    u16* bfcC = sm + 6*4*KI;
    u16* bprjC= sm + 7*4*KI;
    int* flag = (int*)(sm + 8*4*KI);
    u16* slotA = ws + 16 * MEG + 64 * KI;   // 4Mi: h / att / h2
    u16* qB    = slotA + 4  * MEG;
    u16* kB    = slotA + 8  * MEG;
    u16* vT    = slotA + 12 * MEG;
    u16* probs = slotA + 16 * MEG;      // chunk*(H,S,S); [0,16Mi) reused as act
    float* part = (float*)(probs + 16 * MEG);  // split-K partials (chunk=4 only)

    const long fixed_elems = 32 * MEG + 64 * KI;
    const long avail = (long)(ws_size / 2);
    int chunk = 1;
    if      (avail >= fixed_elems + 64 * MEG) chunk = 4;
    else if (avail >= fixed_elems + 32 * MEG) chunk = 2;
    const bool splitk = (chunk == 4);

    detect_k<<<1, 256, 0, stream>>>((const u16*)d_in[0], flag);
    conv_w_k<<<12288, 256, 0, stream>>>(d_in[6], d_in[8], d_in[10], d_in[12],
                                        winC, flag);
    conv_small_k<<<52, 256, 0, stream>>>(d_in[2], d_in[3], d_in[4], d_in[5],
                                         d_in[7], d_in[9], d_in[11], d_in[13],
                                         sm, flag);

    u16* h   = slotA;
    u16* att = slotA;
    u16* h2  = slotA;
    u16* act = probs;

    // 1. LN1 (+x conversion)
    ln1x_k<<<4096, 256, 0, stream>>>(d_in[0], ln1g, ln1b, xc, h, flag);
    // 2. QKV projection
    gemm_bt<128, 1><<<dim3(24, 32, 1), 256, 0, stream>>>(
        h, winC, nullptr, binC, nullptr, qB, kB, vT,
        4096, 3072, 1024, 1024, 1024, 0, 0, 0, 0, nullptr, nullptr);
    // 3-6. attention
    for (int b0 = 0; b0 < 4; b0 += chunk) {
        gemm_bt<128, 4><<<dim3(8, 8, 16 * chunk), 256, 0, stream>>>(
            qB + b0 * MEG, kB + b0 * MEG, probs, nullptr, nullptr,
            nullptr, nullptr, nullptr,
            1024, 1024, 64, 64, 64, 1024, 65536, 65536, 1048576, nullptr, nullptr);
        softmax_k<<<4096 * chunk, 256, 0, stream>>>(probs);
        gemm_bt<64, 5><<<dim3(1, 8, 16 * chunk), 256, 0, stream>>>(
            probs, vT + b0 * MEG, att + b0 * MEG, nullptr, nullptr,
            nullptr, nullptr, nullptr,
            1024, 64, 1024, 1024, 1024, 1024, 1048576, 65536, 0, nullptr, nullptr);
        mean_k<<<512 * chunk, 256, 0, stream>>>(probs, d_out, 4 * MEG + b0 * MEG, flag);
    }
    // 7+8. x2 = x + att @ w_out^T + b_out; h2 = LN2(x2)
    if (splitk) {
        gemm_bt<128, 7><<<dim3(8, 32, 2), 256, 0, stream>>>(
            att, woutC, nullptr, nullptr, nullptr, nullptr, nullptr, nullptr,
            4096, 1024, 512, 1024, 1024, 1024, 512, 512, 4 * MEG, nullptr, part);
        redln_k<<<4096, 256, 0, stream>>>(part, 4 * MEG, boutC, xc, ln2g, ln2b, h2);
    } else {
        gemm_bt<128, 2><<<dim3(8, 32, 1), 256, 0, stream>>>(
            att, woutC, xc, boutC, xc, nullptr, nullptr, nullptr,
            4096, 1024, 1024, 1024, 1024, 1024, 0, 0, 0, nullptr, nullptr);
        ln_k<<<4096, 256, 0, stream>>>(xc, ln2g, ln2b, h2);
    }
    // 9. act = gelu(h2 @ w_fc^T + b_fc)
    gemm_bt<128, 3><<<dim3(32, 32, 1), 256, 0, stream>>>(
        h2, wfcC, act, bfcC, nullptr, nullptr, nullptr, nullptr,
        4096, 4096, 1024, 1024, 1024, 4096, 0, 0, 0, nullptr, nullptr);
    // 10. out = x2 + act @ w_proj^T + b_proj
    if (splitk) {
        gemm_bt<128, 7><<<dim3(8, 32, 4), 256, 0, stream>>>(
            act, wprjC, nullptr, nullptr, nullptr, nullptr, nullptr, nullptr,
            4096, 1024, 1024, 4096, 4096, 1024, 1024, 1024, 4 * MEG, nullptr, part);
        reduce_out_k<<<4096, 256, 0, stream>>>(part, 4 * MEG, bprjC, xc, d_out, flag);
    } else {
        gemm_bt<128, 6><<<dim3(8, 32, 1), 256, 0, stream>>>(
            act, wprjC, nullptr, bprjC, xc, nullptr, nullptr, nullptr,
            4096, 1024, 4096, 4096, 4096, 1024, 0, 0, 0, flag, d_out);
    }
}

// Round 8
// 487.110 us; speedup vs baseline: 1.1013x; 1.0655x over previous
//
#include <hip/hip_runtime.h>

typedef unsigned short u16;
typedef u16   u16x4 __attribute__((ext_vector_type(4)));
typedef u16   u16x8 __attribute__((ext_vector_type(8)));
typedef short s16x8 __attribute__((ext_vector_type(8)));
typedef float f32x4 __attribute__((ext_vector_type(4)));

__device__ __forceinline__ float b2f(u16 u) {
    union { unsigned int i; float f; } v; v.i = ((unsigned int)u) << 16; return v.f;
}
__device__ __forceinline__ u16 f2b(float f) {
    union { float f; unsigned int i; } v; v.f = f;
    unsigned int r = v.i + 0x7fffu + ((v.i >> 16) & 1u);
    return (u16)(r >> 16);
}
__device__ __forceinline__ float gelu_f(float x) {
    float z = 0.7978845608028654f * (x + 0.044715f * x * x * x);
    float e = __expf(2.0f * z);
    float t = 1.0f - 2.0f / (e + 1.0f);
    return 0.5f * x * (1.0f + t);
}
__device__ __forceinline__ void async16(const u16* g, u16* l) {
    __builtin_amdgcn_global_load_lds(
        (const __attribute__((address_space(1))) unsigned int*)g,
        (__attribute__((address_space(3))) unsigned int*)l,
        16, 0, 0);
}

// ---- dtype detector: bf16-read exponent >= 2^60 anywhere => fp32 input
__global__ __launch_bounds__(256)
void detect_k(const u16* __restrict__ x, int* __restrict__ flag)
{
    int tid = threadIdx.x;
    int bad = 0;
    for (int i = tid; i < 65536; i += 256) {
        int e = (x[i] >> 7) & 0xFF;
        if (e >= 187) bad = 1;
    }
    unsigned long long m = __ballot(bad != 0);
    __shared__ int sh[4];
    if ((tid & 63) == 0) sh[tid >> 6] = (m != 0ull) ? 1 : 0;
    __syncthreads();
    if (tid == 0) flag[0] = sh[0] | sh[1] | sh[2] | sh[3];
}

// ---- weight converter (vec4): w_in|w_out|w_fc|w_proj -> ws[4Mi..16Mi)
__global__ __launch_bounds__(256)
void conv_w_k(const void* __restrict__ s0, const void* __restrict__ s1,
              const void* __restrict__ s2, const void* __restrict__ s3,
              u16* __restrict__ dst, const int* __restrict__ flag)
{
    const long MEG = 1L << 20;
    long gid = ((long)blockIdx.x * 256 + threadIdx.x) * 4;   // < 12Mi
    const void* s; long off;
    if      (gid <  3*MEG) { s = s0; off = gid; }
    else if (gid <  4*MEG) { s = s1; off = gid - 3*MEG; }
    else if (gid <  8*MEG) { s = s2; off = gid - 4*MEG; }
    else                   { s = s3; off = gid - 8*MEG; }
    u16x4 o;
    if (*flag) {
        const float4 f = *(const float4*)((const float*)s + off);
        o[0] = f2b(f.x); o[1] = f2b(f.y); o[2] = f2b(f.z); o[3] = f2b(f.w);
    } else {
        o = *(const u16x4*)((const u16*)s + off);
    }
    *(u16x4*)(dst + gid) = o;
}

// ---- fused small-param converter into 4Ki-slotted region
__global__ __launch_bounds__(256)
void conv_small_k(const void* s0, const void* s1, const void* s2, const void* s3,
                  const void* s4, const void* s5, const void* s6, const void* s7,
                  u16* __restrict__ dst, const int* __restrict__ flag)
{
    int gid = blockIdx.x * 256 + threadIdx.x;          // < 13312
    int seg, off;
    if      (gid <  4096) { seg = gid >> 10;  off = gid & 1023; }
    else if (gid <  7168) { seg = 4; off = gid - 4096; }
    else if (gid <  8192) { seg = 5; off = gid - 7168; }
    else if (gid < 12288) { seg = 6; off = gid - 8192; }
    else                  { seg = 7; off = gid - 12288; }
    const void* srcs[8] = {s0, s1, s2, s3, s4, s5, s6, s7};
    const void* s = srcs[seg];
    dst[seg * 4096 + off] = (*flag) ? f2b(((const float*)s)[off]) : ((const u16*)s)[off];
}

// ---- LN1 fused with x conversion
__global__ __launch_bounds__(256)
void ln1x_k(const void* __restrict__ xraw, const u16* __restrict__ g,
            const u16* __restrict__ b, u16* __restrict__ xc,
            u16* __restrict__ o, const int* __restrict__ flag)
{
    long row = blockIdx.x;
    int tid = threadIdx.x;
    float v0, v1, v2, v3;
    if (*flag) {
        const float4 f = *(const float4*)((const float*)xraw + row * 1024 + tid * 4);
        v0 = b2f(f2b(f.x)); v1 = b2f(f2b(f.y));
        v2 = b2f(f2b(f.z)); v3 = b2f(f2b(f.w));
    } else {
        const u16x4 u = *(const u16x4*)((const u16*)xraw + row * 1024 + tid * 4);
        v0 = b2f(u[0]); v1 = b2f(u[1]); v2 = b2f(u[2]); v3 = b2f(u[3]);
    }
    u16x4 xv; xv[0] = f2b(v0); xv[1] = f2b(v1); xv[2] = f2b(v2); xv[3] = f2b(v3);
    *(u16x4*)(xc + row * 1024 + tid * 4) = xv;
    float s  = v0 + v1 + v2 + v3;
    float sq = v0*v0 + v1*v1 + v2*v2 + v3*v3;
    #pragma unroll
    for (int off = 32; off; off >>= 1) { s += __shfl_xor(s, off); sq += __shfl_xor(sq, off); }
    __shared__ float sm[8];
    int wid = tid >> 6, lane = tid & 63;
    if (lane == 0) { sm[wid] = s; sm[wid + 4] = sq; }
    __syncthreads();
    s  = sm[0] + sm[1] + sm[2] + sm[3];
    sq = sm[4] + sm[5] + sm[6] + sm[7];
    float mean = s * (1.0f / 1024.0f);
    float var  = sq * (1.0f / 1024.0f) - mean * mean;
    float rs   = rsqrtf(var + 1e-5f);
    u16x4 gg = *(const u16x4*)(g + tid * 4);
    u16x4 bb = *(const u16x4*)(b + tid * 4);
    u16x4 ov;
    ov[0] = f2b((v0 - mean) * rs * b2f(gg[0]) + b2f(bb[0]));
    ov[1] = f2b((v1 - mean) * rs * b2f(gg[1]) + b2f(bb[1]));
    ov[2] = f2b((v2 - mean) * rs * b2f(gg[2]) + b2f(bb[2]));
    ov[3] = f2b((v3 - mean) * rs * b2f(gg[3]) + b2f(bb[3]));
    *(u16x4*)(o + row * 1024 + tid * 4) = ov;
}

// ---- plain LN (fallback path)
__global__ __launch_bounds__(256)
void ln_k(const u16* __restrict__ x, const u16* __restrict__ g,
          const u16* __restrict__ b, u16* __restrict__ o)
{
    long row = blockIdx.x;
    int tid = threadIdx.x;
    const u16x4 u = *(const u16x4*)(x + row * 1024 + tid * 4);
    float v0 = b2f(u[0]), v1 = b2f(u[1]), v2 = b2f(u[2]), v3 = b2f(u[3]);
    float s  = v0 + v1 + v2 + v3;
    float sq = v0*v0 + v1*v1 + v2*v2 + v3*v3;
    #pragma unroll
    for (int off = 32; off; off >>= 1) { s += __shfl_xor(s, off); sq += __shfl_xor(sq, off); }
    __shared__ float sm[8];
    int wid = tid >> 6, lane = tid & 63;
    if (lane == 0) { sm[wid] = s; sm[wid + 4] = sq; }
    __syncthreads();
    s  = sm[0] + sm[1] + sm[2] + sm[3];
    sq = sm[4] + sm[5] + sm[6] + sm[7];
    float mean = s * (1.0f / 1024.0f);
    float var  = sq * (1.0f / 1024.0f) - mean * mean;
    float rs   = rsqrtf(var + 1e-5f);
    u16x4 gg = *(const u16x4*)(g + tid * 4);
    u16x4 bb = *(const u16x4*)(b + tid * 4);
    u16x4 ov;
    ov[0] = f2b((v0 - mean) * rs * b2f(gg[0]) + b2f(bb[0]));
    ov[1] = f2b((v1 - mean) * rs * b2f(gg[1]) + b2f(bb[1]));
    ov[2] = f2b((v2 - mean) * rs * b2f(gg[2]) + b2f(bb[2]));
    ov[3] = f2b((v3 - mean) * rs * b2f(gg[3]) + b2f(bb[3]));
    *(u16x4*)(o + row * 1024 + tid * 4) = ov;
}

// ---- fused split-K(2) reduce + LN2
__global__ __launch_bounds__(256)
void redln_k(const float* __restrict__ P, long slice,
             const u16* __restrict__ bias, u16* __restrict__ res,
             const u16* __restrict__ g, const u16* __restrict__ b,
             u16* __restrict__ o)
{
    long row = blockIdx.x;
    int tid = threadIdx.x;
    long i = row * 1024 + tid * 4;
    float4 v  = *(const float4*)(P + i);
    float4 p1 = *(const float4*)(P + slice + i);
    u16x4 bb = *(const u16x4*)(bias + tid * 4);
    u16x4 rr = *(const u16x4*)(res + i);
    float v0 = b2f(f2b(v.x + p1.x + b2f(bb[0]) + b2f(rr[0])));
    float v1 = b2f(f2b(v.y + p1.y + b2f(bb[1]) + b2f(rr[1])));
    float v2 = b2f(f2b(v.z + p1.z + b2f(bb[2]) + b2f(rr[2])));
    float v3 = b2f(f2b(v.w + p1.w + b2f(bb[3]) + b2f(rr[3])));
    u16x4 xv; xv[0] = f2b(v0); xv[1] = f2b(v1); xv[2] = f2b(v2); xv[3] = f2b(v3);
    *(u16x4*)(res + i) = xv;
    float s  = v0 + v1 + v2 + v3;
    float sq = v0*v0 + v1*v1 + v2*v2 + v3*v3;
    #pragma unroll
    for (int off = 32; off; off >>= 1) { s += __shfl_xor(s, off); sq += __shfl_xor(sq, off); }
    __shared__ float sm[8];
    int wid = tid >> 6, lane = tid & 63;
    if (lane == 0) { sm[wid] = s; sm[wid + 4] = sq; }
    __syncthreads();
    s  = sm[0] + sm[1] + sm[2] + sm[3];
    sq = sm[4] + sm[5] + sm[6] + sm[7];
    float mean = s * (1.0f / 1024.0f);
    float var  = sq * (1.0f / 1024.0f) - mean * mean;
    float rs   = rsqrtf(var + 1e-5f);
    u16x4 gg = *(const u16x4*)(g + tid * 4);
    u16x4 b2 = *(const u16x4*)(b + tid * 4);
    u16x4 ov;
    ov[0] = f2b((v0 - mean) * rs * b2f(gg[0]) + b2f(b2[0]));
    ov[1] = f2b((v1 - mean) * rs * b2f(gg[1]) + b2f(b2[1]));
    ov[2] = f2b((v2 - mean) * rs * b2f(gg[2]) + b2f(b2[2]));
    ov[3] = f2b((v3 - mean) * rs * b2f(gg[3]) + b2f(b2[3]));
    *(u16x4*)(o + row * 1024 + tid * 4) = ov;
}

// -------- Fused softmax (causal, in-place) + mean-over-heads ----------
// One block per (chunk-batch, q-row): 16 waves = 16 heads; fp32 probs
// round-trip LDS, block-reduce over heads -> att_weights row.
__global__ __launch_bounds__(1024)
void smmean_k(u16* __restrict__ probs, void* __restrict__ ow, long ofs,
              const int* __restrict__ flag)
{
    const long MEG = 1L << 20;
    __shared__ float red[16 * 1024];
    int bl = blockIdx.x >> 10;           // batch within chunk
    int q  = blockIdx.x & 1023;
    int w = threadIdx.x >> 6, lane = threadIdx.x & 63;
    int tile_end = ((q >> 7) + 1) << 7;
    u16* row = probs + (((long)(bl * 16 + w)) << 20) + (long)q * 1024;
    float v[16];
    float m = -3.0e38f;
    #pragma unroll
    for (int c = 0; c < 2; c++) {
        int kb = (c * 64 + lane) * 8;
        if (kb <= q) {
            u16x8 u = *(const u16x8*)(row + kb);
            #pragma unroll
            for (int e = 0; e < 8; e++) {
                if (kb + e <= q) {
                    float f = b2f(u[e]);
                    v[c * 8 + e] = f;
                    m = fmaxf(m, f);
                } else v[c * 8 + e] = -3.0e38f;
            }
        } else {
            #pragma unroll
            for (int e = 0; e < 8; e++) v[c * 8 + e] = -3.0e38f;
        }
    }
    #pragma unroll
    for (int off = 32; off; off >>= 1) m = fmaxf(m, __shfl_xor(m, off));
    float s = 0.0f;
    #pragma unroll
    for (int t = 0; t < 16; t++) {
        float e = (v[t] > -1.0e38f) ? __expf(v[t] - m) : 0.0f;
        v[t] = e; s += e;
    }
    #pragma unroll
    for (int off = 32; off; off >>= 1) s += __shfl_xor(s, off);
    float inv = 1.0f / s;
    #pragma unroll
    for (int c = 0; c < 2; c++) {
        int kb = (c * 64 + lane) * 8;
        float p[8];
        #pragma unroll
        for (int e = 0; e < 8; e++) p[e] = v[c * 8 + e] * inv;
        // stash fp32 probs for the head-mean
        #pragma unroll
        for (int e = 0; e < 8; e++) red[w * 1024 + kb + e] = p[e];
        if (kb < tile_end) {
            u16x8 o;
            #pragma unroll
            for (int e = 0; e < 8; e++) o[e] = f2b(p[e]);
            *(u16x8*)(row + kb) = o;
        }
    }
    __syncthreads();
    int t = threadIdx.x;
    float acc = 0.0f;
    #pragma unroll
    for (int h = 0; h < 16; h++) acc += red[h * 1024 + t];
    acc *= 0.0625f;
    long idx = ofs + (long)bl * MEG + (long)q * 1024 + t;
    if (*flag) ((float*)ow)[idx] = acc;
    else       ((u16*)ow)[idx]   = f2b(acc);
}

// -------- split-K(4) reduce for final output --------
__global__ __launch_bounds__(256)
void reduce_out_k(const float* __restrict__ P, long slice,
                  const u16* __restrict__ bias, const u16* __restrict__ res,
                  void* __restrict__ out, const int* __restrict__ flag)
{
    long i = ((long)blockIdx.x * 256 + threadIdx.x) * 4;
    int gn = (int)(i & 1023);
    float4 v = *(const float4*)(P + i);
    #pragma unroll
    for (int s = 1; s < 4; s++) {
        const float4 p = *(const float4*)(P + (long)s * slice + i);
        v.x += p.x; v.y += p.y; v.z += p.z; v.w += p.w;
    }
    u16x4 bb = *(const u16x4*)(bias + gn);
    u16x4 rr = *(const u16x4*)(res + i);
    v.x += b2f(bb[0]) + b2f(rr[0]);
    v.y += b2f(bb[1]) + b2f(rr[1]);
    v.z += b2f(bb[2]) + b2f(rr[2]);
    v.w += b2f(bb[3]) + b2f(rr[3]);
    if (*flag) {
        *(float4*)((float*)out + i) = v;
    } else {
        u16x4 o;
        o[0] = f2b(v.x); o[1] = f2b(v.y); o[2] = f2b(v.z); o[3] = f2b(v.w);
        *(u16x4*)((u16*)out + i) = o;
    }
}

// ---------------- gemm_bt: C[m,n] = sum_k A[m,k]*Bt[n,k] + epilogue ---
// EPI: 1 qkv-routing (+bias, v via LDS transpose), 2 +bias+residual,
//      3 gelu(+bias), 4 scores (scale+causal), 5 PV (k-limit),
//      6 +bias+residual flag-adaptive, 7 split-K fp32 partial
template<int BN, int EPI>
__global__ __launch_bounds__(256)
void gemm_bt(const u16* __restrict__ A, const u16* __restrict__ Bt,
             u16* __restrict__ C, const u16* __restrict__ bias,
             const u16* __restrict__ res,
             u16* __restrict__ qb, u16* __restrict__ kb, u16* __restrict__ vb,
             int M, int N, int K, int lda, int ldb, int ldc,
             long sA, long sB, long sC,
             const int* __restrict__ oflag, void* __restrict__ oout)
{
    constexpr int BM = 128, BK = 32;
    constexpr int WROWS = (BN == 128) ? 2 : 4;
    constexpr int WCOLS = (BN == 128) ? 2 : 1;
    constexpr int WM = BM / WROWS, WN = BN / WCOLS;
    constexpr int MI = WM / 16, NJ = WN / 16;
    constexpr int BCH = BN * BK / 8 / 256;
    constexpr int SHSZ = 2 * BM * BK + 2 * BN * BK;   // u16 units

    __shared__ alignas(16) u16 shmem[SHSZ];
    u16* AshB = shmem;                 // 2 × BM*BK
    u16* BshB = shmem + 2 * BM * BK;   // 2 × BN*BK
    u16* Csh  = shmem;                 // EPI==1 epilogue reuse (16384 u16)

    const int tid = threadIdx.x;
    int tn = blockIdx.x, tm = blockIdx.y;
    const int bz = blockIdx.z;
    if (EPI == 4 && tn > tm) return;

    // XCD-aware swizzle (A-panel locality); requires gridDim.y % 8 == 0
    if (EPI == 1 || EPI == 2 || EPI == 3 || EPI == 6 || EPI == 7) {
        int L = blockIdx.y * gridDim.x + blockIdx.x;
        int xcd = L & 7, idx = L >> 3;
        tn = idx % gridDim.x;
        tm = (idx / gridDim.x) * 8 + xcd;
    }

    const u16* Ab = A + (long)bz * sA;
    const u16* Bb = Bt + (long)bz * sB;

    const int m0 = tm * BM, n0 = tn * BN;
    const int kEff = (EPI == 5) ? (((tm + 1) * BM < K) ? (tm + 1) * BM : K) : K;

    const int w = tid >> 6, lane = tid & 63;
    const int wrow = w % WROWS, wcol = w / WROWS;
    const int mw = wrow * WM, nw = wcol * WN;
    const int lr = lane & 15, quad = lane >> 4;

    const int ca0 = tid, ca1 = 256 + tid;
    const int ar0 = ca0 >> 2, ac0 = (ca0 & 3) * 8;
    const int ar1 = ca1 >> 2, ac1 = (ca1 & 3) * 8;
    const int br0 = tid >> 2, bc0 = (tid & 3) * 8;
    const int cb1 = 256 + tid;
    const int br1 = cb1 >> 2, bc1 = (cb1 & 3) * 8;

    auto stage = [&](int buf, int k0) {
        async16(Ab + (long)(m0 + ar0) * lda + k0 + ac0, &AshB[buf * BM * BK + ca0 * 8]);
        async16(Ab + (long)(m0 + ar1) * lda + k0 + ac1, &AshB[buf * BM * BK + ca1 * 8]);
        async16(Bb + (long)(n0 + br0) * ldb + k0 + bc0, &BshB[buf * BN * BK + tid * 8]);
        if (BCH == 2)
            async16(Bb + (long)(n0 + br1) * ldb + k0 + bc1, &BshB[buf * BN * BK + cb1 * 8]);
    };

    f32x4 acc[MI][NJ] = {};

    stage(0, 0);
    int cur = 0;
    for (int k0 = 0; k0 < kEff; k0 += BK) {
        __syncthreads();
        if (k0 + BK < kEff) stage(cur ^ 1, k0 + BK);

        s16x8 af[MI], bfr[NJ];
        #pragma unroll
        for (int i = 0; i < MI; i++)
            af[i] = *(const s16x8*)&AshB[cur * BM * BK + (mw + i * 16 + lr) * BK + quad * 8];
        #pragma unroll
        for (int j = 0; j < NJ; j++)
            bfr[j] = *(const s16x8*)&BshB[cur * BN * BK + (nw + j * 16 + lr) * BK + quad * 8];
        #pragma unroll
        for (int i = 0; i < MI; i++)
            #pragma unroll
            for (int j = 0; j < NJ; j++)
                acc[i][j] = __builtin_amdgcn_mfma_f32_16x16x32_bf16(af[i], bfr[j], acc[i][j], 0, 0, 0);
        cur ^= 1;
    }

    if (EPI == 1) {
        const int sel = n0 >> 10;      // 0=q 1=k 2=v (tile within one section)
        const int b = m0 >> 10, sbase = m0 & 1023;
        if (sel < 2) {
            u16* dst = (sel == 0) ? qb : kb;
            #pragma unroll
            for (int i = 0; i < MI; i++)
                #pragma unroll
                for (int j = 0; j < NJ; j++)
                    #pragma unroll
                    for (int r = 0; r < 4; r++) {
                        int gm = m0 + mw + i * 16 + quad * 4 + r;
                        int gn = n0 + nw + j * 16 + lr;
                        float v = acc[i][j][r] + b2f(bias[gn]);
                        int s = gm & 1023, nn = gn & 1023, hh = nn >> 6, d = nn & 63;
                        dst[(((long)(b * 16 + hh) * 1024 + s) << 6) + d] = f2b(v);
                    }
        } else {
            // v: transpose via XOR-swizzled LDS, then coalesced d-row stores
            __syncthreads();           // all waves done reading A/B staging
            #pragma unroll
            for (int i = 0; i < MI; i++)
                #pragma unroll
                for (int j = 0; j < NJ; j++)
                    #pragma unroll
                    for (int r = 0; r < 4; r++) {
                        int nl = nw + j * 16 + lr;
                        int ml = mw + i * 16 + quad * 4 + r;
                        float v = acc[i][j][r] + b2f(bias[n0 + nl]);
                        Csh[nl * 128 + (((ml >> 3) ^ (nl & 15)) << 3) + (ml & 7)] = f2b(v);
                    }
            __syncthreads();
            const int nv0 = n0 - 2048;
            #pragma unroll
            for (int rep = 0; rep < 8; rep++) {
                int dd = rep * 16 + (tid >> 4);
                int sl = (tid & 15) * 8;
                int dg = nv0 + dd, hh = dg >> 6, dcol = dg & 63;
                u16x8 val = *(const u16x8*)&Csh[dd * 128 + ((((sl >> 3)) ^ (dd & 15)) << 3)];
                *(u16x8*)&vb[(((long)(b * 16 + hh) * 64 + dcol) << 10) + sbase + sl] = val;
            }
        }
        return;
    }

    u16* Cb;
    if (EPI == 5) Cb = C + (long)(bz >> 4) * (1 << 20) + (bz & 15) * 64;
    else          Cb = C + (long)bz * sC;

    #pragma unroll
    for (int i = 0; i < MI; i++) {
        #pragma unroll
        for (int j = 0; j < NJ; j++) {
            #pragma unroll
            for (int r = 0; r < 4; r++) {
                int gm = m0 + mw + i * 16 + quad * 4 + r;
                int gn = n0 + nw + j * 16 + lr;
                float v = acc[i][j][r];
                if (EPI == 5) {
                    Cb[(long)gm * ldc + gn] = f2b(v);
                } else if (EPI == 2) {
                    v += b2f(bias[gn]) + b2f(res[(long)gm * ldc + gn]);
                    Cb[(long)gm * ldc + gn] = f2b(v);
                } else if (EPI == 3) {
                    Cb[(long)gm * ldc + gn] = f2b(gelu_f(v + b2f(bias[gn])));
                } else if (EPI == 4) {
                    if (gn <= gm) Cb[(long)gm * ldc + gn] = f2b(v * 0.125f);
                } else if (EPI == 6) {
                    v += b2f(bias[gn]) + b2f(res[(long)gm * ldc + gn]);
                    long idx = (long)gm * ldc + gn;
                    if (*oflag) ((float*)oout)[idx] = v;
                    else        ((u16*)oout)[idx]   = f2b(v);
                } else if (EPI == 7) {
                    ((float*)oout)[(long)bz * sC + (long)gm * ldc + gn] = v;
                }
            }
        }
    }
}

extern "C" void kernel_launch(void* const* d_in, const int* in_sizes, int n_in,
                              void* d_out, int out_size, void* d_ws, size_t ws_size,
                              hipStream_t stream)
{
    const long MEG = 1L << 20;
    const long KI  = 1024;

    u16* ws = (u16*)d_ws;
    u16* xc    = ws;                    // 4Mi: bf16 x, becomes x2 in-place
    u16* winC  = ws + 4  * MEG;         // 3Mi
    u16* woutC = ws + 7  * MEG;         // 1Mi
    u16* wfcC  = ws + 8  * MEG;         // 4Mi
    u16* wprjC = ws + 12 * MEG;         // 4Mi
    u16* sm    = ws + 16 * MEG;
    u16* ln1g = sm + 0*4*KI, *ln1b = sm + 1*4*KI;
    u16* ln2g = sm + 2*4*KI, *ln2b = sm + 3*4*KI;
    u16* binC = sm + 4*4*KI;
    u16* boutC= sm + 5*4*KI;
    u16* bfcC = sm + 6*4*KI;
    u16* bprjC= sm + 7*4*KI;
    int* flag = (int*)(sm + 8*4*KI);
    u16* slotA = ws + 16 * MEG + 64 * KI;   // 4Mi: h / att / h2
    u16* qB    = slotA + 4  * MEG;
    u16* kB    = slotA + 8  * MEG;
    u16* vT    = slotA + 12 * MEG;
    u16* probs = slotA + 16 * MEG;      // chunk*(H,S,S); [0,16Mi) reused as act
    float* part = (float*)(probs + 16 * MEG);  // split-K partials (chunk=4 only)

    const long fixed_elems = 32 * MEG + 64 * KI;
    const long avail = (long)(ws_size / 2);
    int chunk = 1;
    if      (avail >= fixed_elems + 64 * MEG) chunk = 4;
    else if (avail >= fixed_elems + 32 * MEG) chunk = 2;
    const bool splitk = (chunk == 4);

    detect_k<<<1, 256, 0, stream>>>((const u16*)d_in[0], flag);
    conv_w_k<<<12288, 256, 0, stream>>>(d_in[6], d_in[8], d_in[10], d_in[12],
                                        winC, flag);
    conv_small_k<<<52, 256, 0, stream>>>(d_in[2], d_in[3], d_in[4], d_in[5],
                                         d_in[7], d_in[9], d_in[11], d_in[13],
                                         sm, flag);

    u16* h   = slotA;
    u16* att = slotA;
    u16* h2  = slotA;
    u16* act = probs;

    // 1. LN1 (+x conversion)
    ln1x_k<<<4096, 256, 0, stream>>>(d_in[0], ln1g, ln1b, xc, h, flag);
    // 2. QKV projection
    gemm_bt<128, 1><<<dim3(24, 32, 1), 256, 0, stream>>>(
        h, winC, nullptr, binC, nullptr, qB, kB, vT,
        4096, 3072, 1024, 1024, 1024, 0, 0, 0, 0, nullptr, nullptr);
    // 3-6. attention
    for (int b0 = 0; b0 < 4; b0 += chunk) {
        gemm_bt<128, 4><<<dim3(8, 8, 16 * chunk), 256, 0, stream>>>(
            qB + b0 * MEG, kB + b0 * MEG, probs, nullptr, nullptr,
            nullptr, nullptr, nullptr,
            1024, 1024, 64, 64, 64, 1024, 65536, 65536, 1048576, nullptr, nullptr);
        smmean_k<<<1024 * chunk, 1024, 0, stream>>>(probs, d_out,
                                                    4 * MEG + b0 * MEG, flag);
        gemm_bt<64, 5><<<dim3(1, 8, 16 * chunk), 256, 0, stream>>>(
            probs, vT + b0 * MEG, att + b0 * MEG, nullptr, nullptr,
            nullptr, nullptr, nullptr,
            1024, 64, 1024, 1024, 1024, 1024, 1048576, 65536, 0, nullptr, nullptr);
    }
    // 7+8. x2 = x + att @ w_out^T + b_out; h2 = LN2(x2)
    if (splitk) {
        gemm_bt<128, 7><<<dim3(8, 32, 2), 256, 0, stream>>>(
            att, woutC, nullptr, nullptr, nullptr, nullptr, nullptr, nullptr,
            4096, 1024, 512, 1024, 1024, 1024, 512, 512, 4 * MEG, nullptr, part);
        redln_k<<<4096, 256, 0, stream>>>(part, 4 * MEG, boutC, xc, ln2g, ln2b, h2);
    } else {
        gemm_bt<128, 2><<<dim3(8, 32, 1), 256, 0, stream>>>(
            att, woutC, xc, boutC, xc, nullptr, nullptr, nullptr,
            4096, 1024, 1024, 1024, 1024, 1024, 0, 0, 0, nullptr, nullptr);
        ln_k<<<4096, 256, 0, stream>>>(xc, ln2g, ln2b, h2);
    }
    // 9. act = gelu(h2 @ w_fc^T + b_fc)
    gemm_bt<128, 3><<<dim3(32, 32, 1), 256, 0, stream>>>(
        h2, wfcC, act, bfcC, nullptr, nullptr, nullptr, nullptr,
        4096, 4096, 1024, 1024, 1024, 4096, 0, 0, 0, nullptr, nullptr);
    // 10. out = x2 + act @ w_proj^T + b_proj
    if (splitk) {
        gemm_bt<128, 7><<<dim3(8, 32, 4), 256, 0, stream>>>(
            act, wprjC, nullptr, nullptr, nullptr, nullptr, nullptr, nullptr,
            4096, 1024, 1024, 4096, 4096, 1024, 1024, 1024, 4 * MEG, nullptr, part);
        reduce_out_k<<<4096, 256, 0, stream>>>(part, 4 * MEG, bprjC, xc, d_out, flag);
    } else {
        gemm_bt<128, 6><<<dim3(8, 32, 1), 256, 0, stream>>>(
            act, wprjC, nullptr, bprjC, xc, nullptr, nullptr, nullptr,
            4096, 1024, 4096, 4096, 4096, 1024, 0, 0, 0, flag, d_out);
    }
}